// Round 1
// baseline (3011.167 us; speedup 1.0000x reference)
//
#include <hip/hip_runtime.h>

// ---------------------------------------------------------------------------
// PRGAT fused transformer block on MI355X (gfx950), bf16 MFMA pipeline.
//
// Math restructuring (exact up to bf16 rounding):
//   G    = Wq @ Wk^T                    (512x512)
//   s[b,n,m] = x_n G x_m^T + x_n.(Wq bk) + (Wk bq).x_m + bq.bk
//   attn = softmax(leaky_relu(s/scale))
//   Wvo  = Wv @ Wo ; bvo = bv @ Wo
//   out  = attn @ (x@Wvo + bvo) + bo
//   h    = LN(x + out; g1,be1)                      [stored bf16 in ws]
//   refined = LN(h + relu(h@Wf1+bf1)@Wf2 + bf2; g2,be2)   [fp32 to d_out]
//   score = relu(refined@Ws1+bs1)@ws2 + bs2 ; alpha = softmax_n
//   fused = LN_paramfree(sum_n alpha_n * refined_n)
// ---------------------------------------------------------------------------

typedef __attribute__((ext_vector_type(8))) short s8v;   // 8 x bf16 (4 VGPRs)
typedef __attribute__((ext_vector_type(4))) float f4v;   // MFMA accum

#define MFMA16 __builtin_amdgcn_mfma_f32_16x16x32_bf16

__device__ __forceinline__ unsigned short f2bf(float f) {
  union { float f; unsigned u; } v; v.f = f;
  unsigned u = v.u;
  unsigned r = (u + 0x7FFFu + ((u >> 16) & 1u)) >> 16;   // RNE
  return (unsigned short)r;
}
__device__ __forceinline__ float bf2f(unsigned short h) {
  union { unsigned u; float f; } v; v.u = ((unsigned)h) << 16;
  return v.f;
}

// Stage 64 rows x 512 cols of fp32 -> bf16 into padded LDS [64][520].
#define STAGE64_F32(SRC) do { \
    const float4* sp_ = (const float4*)(SRC); \
    _Pragma("unroll") \
    for (int p_ = 0; p_ < 16; ++p_) { \
      int idx_ = p_ * 512 + tid; \
      int r_ = idx_ >> 7, c_ = (idx_ & 127) << 2; \
      float4 v_ = sp_[idx_]; \
      uint2 w_; \
      w_.x = (unsigned)f2bf(v_.x) | ((unsigned)f2bf(v_.y) << 16); \
      w_.y = (unsigned)f2bf(v_.z) | ((unsigned)f2bf(v_.w) << 16); \
      *(uint2*)(xs + r_ * 520 + c_) = w_; \
    } } while (0)

// K-loop: 64 rows x 512 cols, K=512, A in LDS xs[64][520], B bf16 [n][LDB].
// Wave w: rw=w>>2 picks 32-row half, cw=w&3 picks 128-col quarter.
#define KLOOP_512(BT, LDB) do { \
    const int ar0_ = (rw * 32 + l15) * 520, ar1_ = (rw * 32 + 16 + l15) * 520; \
    for (int ks_ = 0; ks_ < 16; ++ks_) { \
      int k0_ = ks_ * 32 + quad * 8; \
      s8v a0_ = *(const s8v*)(xs + ar0_ + k0_); \
      s8v a1_ = *(const s8v*)(xs + ar1_ + k0_); \
      _Pragma("unroll") \
      for (int ct_ = 0; ct_ < 8; ++ct_) { \
        int n_ = cw * 128 + ct_ * 16 + l15; \
        s8v b_ = *(const s8v*)((BT) + n_ * (LDB) + k0_); \
        acc[0][ct_] = MFMA16(a0_, b_, acc[0][ct_], 0, 0, 0); \
        acc[1][ct_] = MFMA16(a1_, b_, acc[1][ct_], 0, 0, 0); \
      } \
    } } while (0)

// ---------------------------------------------------------------------------
// Prep kernels (run every launch; ws is re-poisoned by harness)
// ---------------------------------------------------------------------------

// out[d*512+j] = in[j*512+d]  (fp32 512x512 transpose)
__global__ void tr32(const float* __restrict__ in, float* __restrict__ out) {
  int idx = blockIdx.x * 256 + threadIdx.x;
  int d = idx >> 9, j = idx & 511;
  out[idx] = in[j * 512 + d];
}

// C_bf16[i*512+j] = sum_d A[i*512+d] * B[j*512+d]   (512x512x512, NT)
__global__ void nt_small(const float* __restrict__ A, const float* __restrict__ B,
                         unsigned short* __restrict__ C) {
  __shared__ float As[64][68], Bs[64][68];
  int tx = threadIdx.x & 15, ty = threadIdx.x >> 4;
  int i0 = blockIdx.x * 64, j0 = blockIdx.y * 64;
  float acc[4][4] = {};
  for (int d0 = 0; d0 < 512; d0 += 64) {
    #pragma unroll
    for (int p = 0; p < 4; ++p) {
      int idx = p * 256 + threadIdx.x;       // 1024 float4 units
      int r = idx >> 4, c = (idx & 15) << 2;
      *(float4*)&As[r][c] = *(const float4*)&A[(i0 + r) * 512 + d0 + c];
      *(float4*)&Bs[r][c] = *(const float4*)&B[(j0 + r) * 512 + d0 + c];
    }
    __syncthreads();
    for (int dd = 0; dd < 64; ++dd) {
      float ar[4], br[4];
      #pragma unroll
      for (int r = 0; r < 4; ++r) ar[r] = As[ty * 4 + r][dd];
      #pragma unroll
      for (int c = 0; c < 4; ++c) br[c] = Bs[tx * 4 + c][dd];
      #pragma unroll
      for (int r = 0; r < 4; ++r)
        #pragma unroll
        for (int c = 0; c < 4; ++c) acc[r][c] += ar[r] * br[c];
    }
    __syncthreads();
  }
  #pragma unroll
  for (int r = 0; r < 4; ++r)
    #pragma unroll
    for (int c = 0; c < 4; ++c)
      C[(i0 + ty * 4 + r) * 512 + j0 + tx * 4 + c] = f2bf(acc[r][c]);
}

// out_bf16[n*K+k] = in[k*N+n]  (transpose + convert)
__global__ void trcvt(const float* __restrict__ in, unsigned short* __restrict__ out,
                      int K, int N) {
  int idx = blockIdx.x * 256 + threadIdx.x;
  if (idx >= K * N) return;
  int n = idx / K, k = idx - n * K;
  out[idx] = f2bf(in[(size_t)k * N + n]);
}

// u[i]=Wq[i,:].bk  w[j]=Wk[j,:].bq  bvo[d]=sum_j bv[j]Wo[j,d]  c=bq.bk
__global__ void vecprep(const float* __restrict__ wq, const float* __restrict__ wk,
                        const float* __restrict__ wo, const float* __restrict__ bq,
                        const float* __restrict__ bk, const float* __restrict__ bv,
                        float* __restrict__ uvec, float* __restrict__ wvec,
                        float* __restrict__ cvec, float* __restrict__ bvo) {
  int t = threadIdx.x;
  if (blockIdx.x == 0) {
    float s = 0.f; for (int d = 0; d < 512; ++d) s += wq[t * 512 + d] * bk[d];
    uvec[t] = s;
  } else if (blockIdx.x == 1) {
    float s = 0.f; for (int d = 0; d < 512; ++d) s += wk[t * 512 + d] * bq[d];
    wvec[t] = s;
  } else if (blockIdx.x == 2) {
    float s = 0.f; for (int j = 0; j < 512; ++j) s += bv[j] * wo[j * 512 + t];
    bvo[t] = s;
  } else {
    __shared__ float red[512];
    red[t] = bq[t] * bk[t];
    __syncthreads();
    for (int o = 256; o; o >>= 1) { if (t < o) red[t] += red[t + o]; __syncthreads(); }
    if (t == 0) cvec[0] = red[0];
  }
}

// ---------------------------------------------------------------------------
// K1: z = x @ G^T (never stored); epilogue computes attention weights.
// ---------------------------------------------------------------------------
__global__ __launch_bounds__(512, 2) void k1_attn(
    const float* __restrict__ x, const unsigned short* __restrict__ gqk,
    const float* __restrict__ uvec, const float* __restrict__ wvec,
    const float* __restrict__ cvec, float* __restrict__ attn) {
  __shared__ unsigned short xs[64 * 520];
  __shared__ float sbuf[32][2][2];
  __shared__ float rru[64];
  __shared__ float rrw[64];
  const int tid = threadIdx.x;
  const int wave = tid >> 6, lane = tid & 63, quad = lane >> 4, l15 = lane & 15;
  const int rw = wave >> 2, cw = wave & 3;
  const size_t row0 = (size_t)blockIdx.x * 64;

  if (tid < 128) ((float*)sbuf)[tid] = 0.f;
  else if (tid < 192) rru[tid - 128] = 0.f;
  else if (tid < 256) rrw[tid - 192] = 0.f;

  STAGE64_F32(x + row0 * 512);
  __syncthreads();

  // per-row bias dots: rru[r]=u.x_r  rrw[r]=w.x_r  (8 threads per row)
  {
    int row = tid >> 3, cb = (tid & 7) * 64;
    float su = 0.f, sw = 0.f;
    for (int c2 = 0; c2 < 64; ++c2) {
      float xv = bf2f(xs[row * 520 + cb + c2]);
      su += xv * uvec[cb + c2];
      sw += xv * wvec[cb + c2];
    }
    atomicAdd(&rru[row], su);
    atomicAdd(&rrw[row], sw);
  }

  f4v acc[2][8] = {};
  KLOOP_512(gqk, 512);

  // partial dots s[b,n,m] += x[2b+n,col] * z[2b+m,col] over this lane's cols
  float part[2][4][2] = {};
  #pragma unroll
  for (int t = 0; t < 2; ++t) {
    #pragma unroll
    for (int ct = 0; ct < 8; ++ct) {
      int col = cw * 128 + ct * 16 + l15;
      #pragma unroll
      for (int g = 0; g < 4; ++g) {
        int m = rw * 32 + t * 16 + quad * 4 + g;
        float zv = acc[t][ct][g];
        int b2 = m & ~1;
        part[t][g][0] += bf2f(xs[b2 * 520 + col]) * zv;
        part[t][g][1] += bf2f(xs[(b2 + 1) * 520 + col]) * zv;
      }
    }
  }
  #pragma unroll
  for (int t = 0; t < 2; ++t)
    #pragma unroll
    for (int g = 0; g < 4; ++g) {
      int m = rw * 32 + t * 16 + quad * 4 + g;
      atomicAdd(&sbuf[m >> 1][0][m & 1], part[t][g][0]);
      atomicAdd(&sbuf[m >> 1][1][m & 1], part[t][g][1]);
    }
  __syncthreads();

  if (tid < 64) {
    int bl = tid >> 1, nn = tid & 1;
    float cc = cvec[0];
    float ru = rru[bl * 2 + nn];
    float scale = sqrtf(512.f) + 1e-8f;
    float s0 = (sbuf[bl][nn][0] + ru + rrw[bl * 2 + 0] + cc) / scale;
    float s1 = (sbuf[bl][nn][1] + ru + rrw[bl * 2 + 1] + cc) / scale;
    s0 = s0 > 0.f ? s0 : 0.2f * s0;
    s1 = s1 > 0.f ? s1 : 0.2f * s1;
    float mx = fmaxf(s0, s1);
    float e0 = expf(s0 - mx), e1 = expf(s1 - mx);
    float inv = 1.f / (e0 + e1);
    size_t gb = (size_t)blockIdx.x * 32 + bl;
    attn[gb * 4 + nn * 2 + 0] = e0 * inv;
    attn[gb * 4 + nn * 2 + 1] = e1 * inv;
  }
}

// ---------------------------------------------------------------------------
// K2: vo = x@Wvo + bvo ; out = attn-mix(vo) + bo ; h = LN(x+out)  -> h bf16
// ---------------------------------------------------------------------------
__global__ __launch_bounds__(512, 2) void k2_proj(
    const float* __restrict__ x, const unsigned short* __restrict__ wvoT,
    const float* __restrict__ bvo, const float* __restrict__ bo,
    const float* __restrict__ attn, const float* __restrict__ g1,
    const float* __restrict__ be1, unsigned short* __restrict__ hout) {
  __shared__ unsigned short xs[64 * 520];
  __shared__ unsigned short vos[64 * 520];
  const int tid = threadIdx.x;
  const int wave = tid >> 6, lane = tid & 63, quad = lane >> 4, l15 = lane & 15;
  const int rw = wave >> 2, cw = wave & 3;
  const size_t row0 = (size_t)blockIdx.x * 64;

  STAGE64_F32(x + row0 * 512);
  __syncthreads();

  f4v acc[2][8] = {};
  KLOOP_512(wvoT, 512);

  #pragma unroll
  for (int t = 0; t < 2; ++t)
    #pragma unroll
    for (int ct = 0; ct < 8; ++ct) {
      int col = cw * 128 + ct * 16 + l15;
      float bb = bvo[col];
      #pragma unroll
      for (int g = 0; g < 4; ++g) {
        int m = rw * 32 + t * 16 + quad * 4 + g;
        vos[m * 520 + col] = f2bf(acc[t][ct][g] + bb);
      }
    }
  __syncthreads();

  for (int rr = 0; rr < 8; ++rr) {
    int r = wave * 8 + rr;
    size_t grow = row0 + r;
    size_t gb = (size_t)blockIdx.x * 32 + (r >> 1);
    float a0 = attn[gb * 4 + (r & 1) * 2 + 0];
    float a1 = attn[gb * 4 + (r & 1) * 2 + 1];
    int c0 = lane * 8;
    int b2 = r & ~1;
    float v[8]; float s = 0.f, s2 = 0.f;
    #pragma unroll
    for (int j = 0; j < 8; ++j) {
      int c = c0 + j;
      float val = bf2f(xs[r * 520 + c]) + a0 * bf2f(vos[b2 * 520 + c]) +
                  a1 * bf2f(vos[(b2 + 1) * 520 + c]) + bo[c];
      v[j] = val; s += val; s2 += val * val;
    }
    #pragma unroll
    for (int o = 32; o; o >>= 1) { s += __shfl_xor(s, o); s2 += __shfl_xor(s2, o); }
    float mu = s * (1.f / 512.f);
    float var = s2 * (1.f / 512.f) - mu * mu;
    float rs = rsqrtf(var + 1e-5f);
    unsigned short o8[8];
    #pragma unroll
    for (int j = 0; j < 8; ++j)
      o8[j] = f2bf((v[j] - mu) * rs * g1[c0 + j] + be1[c0 + j]);
    int4 w4;
    w4.x = (int)((unsigned)o8[0] | ((unsigned)o8[1] << 16));
    w4.y = (int)((unsigned)o8[2] | ((unsigned)o8[3] << 16));
    w4.z = (int)((unsigned)o8[4] | ((unsigned)o8[5] << 16));
    w4.w = (int)((unsigned)o8[6] | ((unsigned)o8[7] << 16));
    *(int4*)(hout + grow * 512 + c0) = w4;
  }
}

// ---------------------------------------------------------------------------
// K3: fused FFN: refined = LN(h + relu(h@Wf1+bf1)@Wf2 + bf2)  -> fp32 d_out
// 32 rows/block; hidden 32x1024 tile lives in LDS.
// ---------------------------------------------------------------------------
__global__ __launch_bounds__(512, 2) void k3_ffn(
    const unsigned short* __restrict__ h, const unsigned short* __restrict__ wf1T,
    const float* __restrict__ bf1, const unsigned short* __restrict__ wf2T,
    const float* __restrict__ bf2, const float* __restrict__ g2,
    const float* __restrict__ be2, float* __restrict__ refined) {
  __shared__ unsigned short hs[32 * 520];    // 33.3 KB
  __shared__ unsigned short us[32 * 1032];   // 66.0 KB
  const int tid = threadIdx.x;
  const int wave = tid >> 6, lane = tid & 63, quad = lane >> 4, l15 = lane & 15;
  const size_t row0 = (size_t)blockIdx.x * 32;

  { // stage h (already bf16): 32*512/8 = 2048 int4
    const int4* sp = (const int4*)(h + row0 * 512);
    #pragma unroll
    for (int p = 0; p < 4; ++p) {
      int idx = p * 512 + tid;
      int r = idx >> 6, c = (idx & 63) << 3;
      *(int4*)(hs + r * 520 + c) = sp[idx];
    }
  }
  __syncthreads();

  // GEMM1: 32 x 1024, K=512; wave owns 128-col slice
  f4v acc1[2][8] = {};
  {
    const int ar0 = l15 * 520, ar1 = (16 + l15) * 520;
    for (int ks = 0; ks < 16; ++ks) {
      int k0 = ks * 32 + quad * 8;
      s8v a0 = *(const s8v*)(hs + ar0 + k0);
      s8v a1 = *(const s8v*)(hs + ar1 + k0);
      #pragma unroll
      for (int ct = 0; ct < 8; ++ct) {
        int n = wave * 128 + ct * 16 + l15;
        s8v b = *(const s8v*)(wf1T + n * 512 + k0);
        acc1[0][ct] = MFMA16(a0, b, acc1[0][ct], 0, 0, 0);
        acc1[1][ct] = MFMA16(a1, b, acc1[1][ct], 0, 0, 0);
      }
    }
  }
  #pragma unroll
  for (int t = 0; t < 2; ++t)
    #pragma unroll
    for (int ct = 0; ct < 8; ++ct) {
      int col = wave * 128 + ct * 16 + l15;
      float bb = bf1[col];
      #pragma unroll
      for (int g = 0; g < 4; ++g) {
        int m = t * 16 + quad * 4 + g;
        us[m * 1032 + col] = f2bf(fmaxf(acc1[t][ct][g] + bb, 0.f));
      }
    }
  __syncthreads();

  // GEMM2: 32 x 512, K=1024; wave owns 64-col slice
  f4v acc2[2][4] = {};
  {
    const int ar0 = l15 * 1032, ar1 = (16 + l15) * 1032;
    for (int ks = 0; ks < 32; ++ks) {
      int k0 = ks * 32 + quad * 8;
      s8v a0 = *(const s8v*)(us + ar0 + k0);
      s8v a1 = *(const s8v*)(us + ar1 + k0);
      #pragma unroll
      for (int ct = 0; ct < 4; ++ct) {
        int n = wave * 64 + ct * 16 + l15;
        s8v b = *(const s8v*)(wf2T + n * 1024 + k0);
        acc2[0][ct] = MFMA16(a0, b, acc2[0][ct], 0, 0, 0);
        acc2[1][ct] = MFMA16(a1, b, acc2[1][ct], 0, 0, 0);
      }
    }
  }
  __syncthreads();  // done reading us; reuse as pre-LN bounce [32][520]

  #pragma unroll
  for (int t = 0; t < 2; ++t)
    #pragma unroll
    for (int ct = 0; ct < 4; ++ct) {
      int col = wave * 64 + ct * 16 + l15;
      float bb = bf2[col];
      #pragma unroll
      for (int g = 0; g < 4; ++g) {
        int m = t * 16 + quad * 4 + g;
        float val = acc2[t][ct][g] + bb + bf2f(hs[m * 520 + col]);
        us[m * 520 + col] = f2bf(val);
      }
    }
  __syncthreads();

  for (int rr = 0; rr < 4; ++rr) {
    int r = wave * 4 + rr;
    size_t grow = row0 + r;
    int c0 = lane * 8;
    float v[8]; float s = 0.f, s2 = 0.f;
    #pragma unroll
    for (int j = 0; j < 8; ++j) {
      float val = bf2f(us[r * 520 + c0 + j]);
      v[j] = val; s += val; s2 += val * val;
    }
    #pragma unroll
    for (int o = 32; o; o >>= 1) { s += __shfl_xor(s, o); s2 += __shfl_xor(s2, o); }
    float mu = s * (1.f / 512.f);
    float var = s2 * (1.f / 512.f) - mu * mu;
    float rs = rsqrtf(var + 1e-5f);
    float4 f0, f1;
    f0.x = (v[0] - mu) * rs * g2[c0 + 0] + be2[c0 + 0];
    f0.y = (v[1] - mu) * rs * g2[c0 + 1] + be2[c0 + 1];
    f0.z = (v[2] - mu) * rs * g2[c0 + 2] + be2[c0 + 2];
    f0.w = (v[3] - mu) * rs * g2[c0 + 3] + be2[c0 + 3];
    f1.x = (v[4] - mu) * rs * g2[c0 + 4] + be2[c0 + 4];
    f1.y = (v[5] - mu) * rs * g2[c0 + 5] + be2[c0 + 5];
    f1.z = (v[6] - mu) * rs * g2[c0 + 6] + be2[c0 + 6];
    f1.w = (v[7] - mu) * rs * g2[c0 + 7] + be2[c0 + 7];
    *(float4*)(refined + grow * 512 + c0) = f0;
    *(float4*)(refined + grow * 512 + c0 + 4) = f1;
  }
}

// ---------------------------------------------------------------------------
// K4: score MLP + softmax pooling + final param-free LN -> fused, alpha
// ---------------------------------------------------------------------------
__global__ __launch_bounds__(512, 2) void k4_pool(
    const float* __restrict__ refined, const unsigned short* __restrict__ ws1T,
    const float* __restrict__ bs1, const float* __restrict__ ws2,
    const float* __restrict__ bs2, float* __restrict__ fused,
    float* __restrict__ alpha) {
  __shared__ unsigned short xs[64 * 520];
  __shared__ float sc[64];
  __shared__ float al[2][32];
  const int tid = threadIdx.x;
  const int wave = tid >> 6, lane = tid & 63, quad = lane >> 4, l15 = lane & 15;
  const int rw = wave >> 2, cw = wave & 3;
  const size_t row0 = (size_t)blockIdx.x * 64;

  if (tid < 64) sc[tid] = 0.f;
  STAGE64_F32(refined + row0 * 512);
  __syncthreads();

  f4v acc[2][8] = {};
  KLOOP_512(ws1T, 512);

  // per-row score partials: relu(acc+bs1[col]) * ws2[col]
  float ps[2][4] = {};
  #pragma unroll
  for (int t = 0; t < 2; ++t)
    #pragma unroll
    for (int ct = 0; ct < 8; ++ct) {
      int col = cw * 128 + ct * 16 + l15;
      float b1 = bs1[col], w2 = ws2[col];
      #pragma unroll
      for (int g = 0; g < 4; ++g) {
        float v = fmaxf(acc[t][ct][g] + b1, 0.f);
        ps[t][g] += v * w2;
      }
    }
  #pragma unroll
  for (int t = 0; t < 2; ++t)
    #pragma unroll
    for (int g = 0; g < 4; ++g) {
      int m = rw * 32 + t * 16 + quad * 4 + g;
      atomicAdd(&sc[m], ps[t][g]);
    }
  __syncthreads();

  if (tid < 32) {
    float s0 = sc[tid * 2 + 0] + bs2[0];
    float s1 = sc[tid * 2 + 1] + bs2[0];
    float mx = fmaxf(s0, s1);
    float e0 = expf(s0 - mx), e1 = expf(s1 - mx);
    float inv = 1.f / (e0 + e1);
    float a0 = e0 * inv, a1 = e1 * inv;
    al[0][tid] = a0; al[1][tid] = a1;
    size_t gb = (size_t)blockIdx.x * 32 + tid;
    alpha[gb * 2 + 0] = a0;
    alpha[gb * 2 + 1] = a1;
  }
  __syncthreads();

  for (int rr = 0; rr < 4; ++rr) {
    int fb = wave * 4 + rr;               // local batch 0..31
    float a0 = al[0][fb], a1 = al[1][fb];
    int c0 = lane * 8;
    float v[8]; float s = 0.f, s2 = 0.f;
    #pragma unroll
    for (int j = 0; j < 8; ++j) {
      int c = c0 + j;
      float val = a0 * bf2f(xs[(fb * 2) * 520 + c]) + a1 * bf2f(xs[(fb * 2 + 1) * 520 + c]);
      v[j] = val; s += val; s2 += val * val;
    }
    #pragma unroll
    for (int o = 32; o; o >>= 1) { s += __shfl_xor(s, o); s2 += __shfl_xor(s2, o); }
    float mu = s * (1.f / 512.f);
    float var = s2 * (1.f / 512.f) - mu * mu;
    float rs = rsqrtf(var + 1e-5f);
    size_t gb = (size_t)blockIdx.x * 32 + fb;
    float4 f0, f1;
    f0.x = (v[0] - mu) * rs; f0.y = (v[1] - mu) * rs;
    f0.z = (v[2] - mu) * rs; f0.w = (v[3] - mu) * rs;
    f1.x = (v[4] - mu) * rs; f1.y = (v[5] - mu) * rs;
    f1.z = (v[6] - mu) * rs; f1.w = (v[7] - mu) * rs;
    *(float4*)(fused + gb * 512 + c0) = f0;
    *(float4*)(fused + gb * 512 + c0 + 4) = f1;
  }
}

// ---------------------------------------------------------------------------
extern "C" void kernel_launch(void* const* d_in, const int* in_sizes, int n_in,
                              void* d_out, int out_size, void* d_ws, size_t ws_size,
                              hipStream_t stream) {
  const float* x   = (const float*)d_in[0];
  const float* wq  = (const float*)d_in[1];
  const float* bq  = (const float*)d_in[2];
  const float* wk  = (const float*)d_in[3];
  const float* bk  = (const float*)d_in[4];
  const float* wv  = (const float*)d_in[5];
  const float* bv  = (const float*)d_in[6];
  const float* wo  = (const float*)d_in[7];
  const float* bo  = (const float*)d_in[8];
  const float* g1  = (const float*)d_in[9];
  const float* be1 = (const float*)d_in[10];
  const float* wf1 = (const float*)d_in[11];
  const float* bf1 = (const float*)d_in[12];
  const float* wf2 = (const float*)d_in[13];
  const float* bf2 = (const float*)d_in[14];
  const float* g2  = (const float*)d_in[15];
  const float* be2 = (const float*)d_in[16];
  const float* ws1 = (const float*)d_in[17];
  const float* bs1 = (const float*)d_in[18];
  const float* ws2 = (const float*)d_in[19];
  const float* bs2 = (const float*)d_in[20];

  char* ws = (char*)d_ws;
  float*          attn = (float*)(ws);                                 // 1 MB
  unsigned short* gqk  = (unsigned short*)(ws + (1u << 20));           // 512 KB
  unsigned short* wvoT = (unsigned short*)(ws + (1u << 20) + 524288);  // 512 KB
  float*          woT  = (float*)(ws + (2u << 20));                    // 1 MB
  unsigned short* wf1T = (unsigned short*)(ws + (3u << 20));           // 1 MB
  unsigned short* wf2T = (unsigned short*)(ws + (4u << 20));           // 1 MB
  unsigned short* ws1T = (unsigned short*)(ws + (5u << 20));           // 512 KB
  float*          uvec = (float*)(ws + (5u << 20) + 524288);
  float*          wvec = uvec + 1024;
  float*          cvec = wvec + 1024;
  float*          bvo  = cvec + 1024;
  unsigned short* h    = (unsigned short*)(ws + (16u << 20));          // 128 MB

  float* fused_out   = (float*)d_out;
  float* alpha_out   = fused_out + (size_t)65536 * 512;
  float* refined_out = alpha_out + (size_t)65536 * 2;

  // --- weight prep ---
  tr32<<<dim3(1024), dim3(256), 0, stream>>>(wo, woT);
  nt_small<<<dim3(8, 8), dim3(256), 0, stream>>>(wq, wk, gqk);    // G = Wq Wk^T
  nt_small<<<dim3(8, 8), dim3(256), 0, stream>>>(woT, wv, wvoT);  // (Wv Wo)^T
  trcvt<<<dim3(2048), dim3(256), 0, stream>>>(wf1, wf1T, 512, 1024);
  trcvt<<<dim3(2048), dim3(256), 0, stream>>>(wf2, wf2T, 1024, 512);
  trcvt<<<dim3(1024), dim3(256), 0, stream>>>(ws1, ws1T, 512, 512);
  vecprep<<<dim3(4), dim3(512), 0, stream>>>(wq, wk, wo, bq, bk, bv, uvec, wvec, cvec, bvo);

  // --- main pipeline ---
  k1_attn<<<dim3(2048), dim3(512), 0, stream>>>(x, gqk, uvec, wvec, cvec, attn);
  k2_proj<<<dim3(2048), dim3(512), 0, stream>>>(x, wvoT, bvo, bo, attn, g1, be1, h);
  k3_ffn<<<dim3(4096), dim3(512), 0, stream>>>(h, wf1T, bf1, wf2T, bf2, g2, be2, refined_out);
  k4_pool<<<dim3(2048), dim3(512), 0, stream>>>(refined_out, ws1T, bs1, ws2, bs2,
                                                fused_out, alpha_out);
}